// Round 6
// baseline (197.890 us; speedup 1.0000x reference)
//
#include <hip/hip_runtime.h>
#include <hip/hip_bf16.h>

#define B_ 8
#define N_ 1024
#define F_ 256
#define OUT_ 256
#define REL_ 16
#define NADJ_ 7

typedef __attribute__((ext_vector_type(8))) _Float16 f16x8;
typedef __attribute__((ext_vector_type(4))) float f32x4;

__device__ __forceinline__ void gll16(const _Float16* g, _Float16* l) {
    __builtin_amdgcn_global_load_lds(
        (const __attribute__((address_space(1))) void*)g,
        (__attribute__((address_space(3))) void*)l, 16, 0, 0);
}

// perm order for slabs: rr 0..3 = r{0,1,3,4} (real adjacency), 4..6 = r{2,5,6} (identity adjacency)
__constant__ const int c_perm[7] = {0, 1, 3, 4, 2, 5, 6};

// ---------------- prep: cbias (blocks 0..6) | transW (7..1798) | cvt feat (1799..2822) ---
__global__ __launch_bounds__(256) void prep_kernel(const float* __restrict__ W,
                                                   const float* __restrict__ We,
                                                   const float* __restrict__ feat,
                                                   float* __restrict__ cb,
                                                   _Float16* __restrict__ WTp,
                                                   _Float16* __restrict__ Fe) {
    int bid = blockIdx.x, tid = threadIdx.x;
    if (bid < 7) {
        int idx = bid * 256 + tid;
        int j = idx / OUT_, o = idx % OUT_;
        int r = c_perm[j];
        const float* Wr = W + (size_t)r * (F_ + REL_) * OUT_;
        float s = 0.f;
#pragma unroll
        for (int d = 0; d < REL_; ++d) s += We[r * REL_ + d] * Wr[(F_ + d) * OUT_ + o];
        cb[idx] = s;
    } else if (bid < 1799) {
        int idx = (bid - 7) * 256 + tid;  // 7*65536 total
        int j = idx >> 16, rem = idx & 65535, o = rem >> 8, f = rem & 255;
        int r = c_perm[j];
        WTp[idx] = (_Float16)W[((size_t)r * (F_ + REL_) + f) * OUT_ + o];
    } else {
        int i = (bid - 1799) * 256 + tid;  // 262144 groups of 8
        size_t base = (size_t)i * 8;
        float4 a = *(const float4*)(feat + base);
        float4 b = *(const float4*)(feat + base + 4);
        f16x8 v = {(_Float16)a.x, (_Float16)a.y, (_Float16)a.z, (_Float16)a.w,
                   (_Float16)b.x, (_Float16)b.y, (_Float16)b.z, (_Float16)b.w};
        *(f16x8*)(Fe + base) = v;
    }
}

// ======= merged: blocks [0,896) = hw7 GEMMs (MFMA) | [896,4992) = convA (memory) =======
// hw7 first so its MFMA overlaps convA's memory streaming on co-resident CUs.
__global__ __launch_bounds__(256) void convhw_kernel(const float* __restrict__ A1,
                                                     const float* __restrict__ A2,
                                                     const _Float16* __restrict__ Fe,
                                                     const _Float16* __restrict__ WTp,
                                                     const float* __restrict__ cb,
                                                     _Float16* __restrict__ Af,
                                                     _Float16* __restrict__ HWT,
                                                     _Float16* __restrict__ HWN) {
    __shared__ _Float16 S[8192];  // hw7: As=S[0..4096), Bs=S[4096..); convA: T=S[0..4096)
    const int bid = blockIdx.x, tid = threadIdx.x;
    if (bid < 896) {
        // hw7: z<4: HWT[z][o][m] = (Fe @ W[z])^T + cb ; z>=4: HWN[z-4][m][o] = Fe @ W[z] + cb
        const int z = bid / 128, rem = bid % 128, bx = rem & 63, by = rem >> 6;
        const bool tr = (z < 4);
        const _Float16* A  = tr ? (WTp + (size_t)z * 65536) : Fe;
        const _Float16* Bt = tr ? Fe : (WTp + (size_t)z * 65536);
        const int m0 = (tr ? by : bx) * 128;
        const int n0 = (tr ? bx : by) * 128;
        _Float16* As = S;
        _Float16* Bs = S + 4096;
        const int wave = tid >> 6, lane = tid & 63, lm = lane & 15, q = lane >> 4;
        const int wr = (wave >> 1) * 64, wc = (wave & 1) * 64;
        const int srow = tid >> 2, sk = (tid & 3) * 8;
        const _Float16* ga0 = A + (size_t)(m0 + srow) * F_ + sk;
        const _Float16* ga1 = ga0 + (size_t)64 * F_;
        const _Float16* gb0 = Bt + (size_t)(n0 + srow) * F_ + sk;
        const _Float16* gb1 = gb0 + (size_t)64 * F_;
        _Float16* la0 = As + tid * 8;
        _Float16* la1 = As + 2048 + tid * 8;
        _Float16* lb0 = Bs + tid * 8;
        _Float16* lb1 = Bs + 2048 + tid * 8;

        f32x4 acc[4][4] = {};
        for (int k0 = 0; k0 < F_; k0 += 32) {
            gll16(ga0 + k0, la0);
            gll16(ga1 + k0, la1);
            gll16(gb0 + k0, lb0);
            gll16(gb1 + k0, lb1);
            __syncthreads();
            f16x8 af[4], bf[4];
#pragma unroll
            for (int i = 0; i < 4; ++i) af[i] = *(const f16x8*)(As + (wr + i * 16 + lm) * 32 + q * 8);
#pragma unroll
            for (int j = 0; j < 4; ++j) bf[j] = *(const f16x8*)(Bs + (wc + j * 16 + lm) * 32 + q * 8);
#pragma unroll
            for (int i = 0; i < 4; ++i)
#pragma unroll
                for (int j = 0; j < 4; ++j)
                    acc[i][j] = __builtin_amdgcn_mfma_f32_16x16x32_f16(af[i], bf[j], acc[i][j], 0, 0, 0);
            __syncthreads();
        }
        const float* cbz = cb + (size_t)z * 256;
        if (tr) {
            _Float16* C = HWT + (size_t)z * ((size_t)256 * 8192);
#pragma unroll
            for (int i = 0; i < 4; ++i)
#pragma unroll
                for (int j = 0; j < 4; ++j)
#pragma unroll
                    for (int g = 0; g < 4; ++g) {
                        int row = wr + i * 16 + q * 4 + g;   // o
                        int col = wc + j * 16 + lm;          // m
                        float v = acc[i][j][g] + cbz[m0 + row];
                        C[(size_t)(m0 + row) * 8192 + (n0 + col)] = (_Float16)v;
                    }
        } else {
            _Float16* C = HWN + (size_t)(z - 4) * ((size_t)8192 * 256);
#pragma unroll
            for (int i = 0; i < 4; ++i)
#pragma unroll
                for (int j = 0; j < 4; ++j)
#pragma unroll
                    for (int g = 0; g < 4; ++g) {
                        int row = wr + i * 16 + q * 4 + g;   // m
                        int col = wc + j * 16 + lm;          // o
                        float v = acc[i][j][g] + cbz[n0 + col];
                        C[(size_t)(m0 + row) * 256 + (n0 + col)] = (_Float16)v;
                    }
        }
    } else {
        // convA: A1/A2 -> f16 straight + transposed slabs, XOR-swizzled LDS transpose
        _Float16* T = S;
        const int cbid = bid - 896;
        int z = cbid >> 8, s = z >> 3, b = z & 7;
        const float* src = (s ? A2 : A1) + (size_t)b * N_ * N_;
        int k0 = (cbid & 15) * 64, n0 = ((cbid >> 4) & 15) * 64;
        int r = tid >> 2, cs = (tid & 3) * 16;
        const float* sp = src + (size_t)(k0 + r) * N_ + n0 + cs;
        _Float16 v[16];
#pragma unroll
        for (int j = 0; j < 16; j += 4) {
            float4 f = *(const float4*)(sp + j);
            v[j] = (_Float16)f.x; v[j + 1] = (_Float16)f.y;
            v[j + 2] = (_Float16)f.z; v[j + 3] = (_Float16)f.w;
        }
        const size_t slab = (size_t)8 * N_ * N_;
        {   // straight: Af[s][b][k0+r][n0+cs..+16]
            _Float16* dst = Af + (size_t)s * slab + (size_t)b * N_ * N_ + (size_t)(k0 + r) * N_ + n0 + cs;
            f16x8 p0 = {v[0], v[1], v[2], v[3], v[4], v[5], v[6], v[7]};
            f16x8 p1 = {v[8], v[9], v[10], v[11], v[12], v[13], v[14], v[15]};
            *(f16x8*)dst = p0;
            *(f16x8*)(dst + 8) = p1;
        }
#pragma unroll
        for (int j = 0; j < 16; ++j) {
            int n = cs + j;
            int sw = ((n ^ (n >> 3)) & 7) << 3;
            T[n * 64 + (r ^ sw)] = v[j];
        }
        __syncthreads();
        {
            int n = tid >> 2, i2 = (tid & 3) * 16;
            int sw = ((n ^ (n >> 3)) & 7) << 3;
            f16x8 q0 = *(const f16x8*)&T[n * 64 + (i2 ^ sw)];
            f16x8 q1 = *(const f16x8*)&T[n * 64 + ((i2 + 8) ^ sw)];
            _Float16* dt = Af + (size_t)(2 + s) * slab + (size_t)b * N_ * N_ + (size_t)(n0 + n) * N_ + k0 + i2;
            *(f16x8*)dt = q0;
            *(f16x8*)(dt + 8) = q1;
        }
    }
}

// ======= fused phase2 + max: out = max_rr(Af[rr][b] @ HWT-tile, HWN[0..2]) + bias =======
// 256 blocks, 128x64 out-tile each. Decode: b = blockIdx.x & 7 -> all 32 blocks of one
// batch land on one XCD (round-robin), 4 ot-siblings (consecutive ids) share A-tiles in L2.
__global__ __launch_bounds__(256) void p2max_kernel(const _Float16* __restrict__ Af,
                                                    const _Float16* __restrict__ HWT,
                                                    const _Float16* __restrict__ HWN,
                                                    const float* __restrict__ bias,
                                                    float* __restrict__ out) {
    __shared__ _Float16 As[128 * 32];
    __shared__ _Float16 Bs[64 * 32];
    const int d = blockIdx.x;
    const int b = d & 7, ot = (d >> 3) & 3, nt = d >> 5;
    const int n0 = nt * 128, o0 = ot * 64;
    const int tid = threadIdx.x;
    const int wave = tid >> 6, lane = tid & 63, lm = lane & 15, q = lane >> 4;
    const int wr = (wave >> 1) * 64, wc = (wave & 1) * 32;
    const int srow = tid >> 2, sk = (tid & 3) * 8;
    _Float16* la0 = As + tid * 8;
    _Float16* la1 = As + 2048 + tid * 8;
    _Float16* lb0 = Bs + tid * 8;

    f32x4 mx[4][2];
#pragma unroll
    for (int i = 0; i < 4; ++i)
#pragma unroll
        for (int j = 0; j < 2; ++j) mx[i][j] = f32x4{-3e38f, -3e38f, -3e38f, -3e38f};

#pragma unroll 1
    for (int rr = 0; rr < 4; ++rr) {
        const _Float16* ga0 = Af + (size_t)rr * (8 * 1048576) + (size_t)b * 1048576
                              + (size_t)(n0 + srow) * N_ + sk;
        const _Float16* ga1 = ga0 + (size_t)64 * N_;
        const _Float16* gb0 = HWT + (size_t)rr * (256 * 8192)
                              + (size_t)(o0 + srow) * 8192 + (size_t)b * 1024 + sk;
        f32x4 acc[4][2] = {};
        for (int k0 = 0; k0 < N_; k0 += 32) {
            gll16(ga0 + k0, la0);
            gll16(ga1 + k0, la1);
            gll16(gb0 + k0, lb0);
            __syncthreads();
            f16x8 af[4], bf[2];
#pragma unroll
            for (int i = 0; i < 4; ++i) af[i] = *(const f16x8*)(As + (wr + i * 16 + lm) * 32 + q * 8);
#pragma unroll
            for (int j = 0; j < 2; ++j) bf[j] = *(const f16x8*)(Bs + (wc + j * 16 + lm) * 32 + q * 8);
#pragma unroll
            for (int i = 0; i < 4; ++i)
#pragma unroll
                for (int j = 0; j < 2; ++j)
                    acc[i][j] = __builtin_amdgcn_mfma_f32_16x16x32_f16(af[i], bf[j], acc[i][j], 0, 0, 0);
            __syncthreads();
        }
#pragma unroll
        for (int i = 0; i < 4; ++i)
#pragma unroll
            for (int j = 0; j < 2; ++j)
#pragma unroll
                for (int g = 0; g < 4; ++g) mx[i][j][g] = fmaxf(mx[i][j][g], acc[i][j][g]);
    }
    // epilogue: fold identity-relation HW slabs + bias
    const size_t slab = (size_t)B_ * N_ * OUT_;
#pragma unroll
    for (int i = 0; i < 4; ++i)
#pragma unroll
        for (int j = 0; j < 2; ++j)
#pragma unroll
            for (int g = 0; g < 4; ++g) {
                int row = wr + i * 16 + q * 4 + g;   // n-local
                int col = wc + j * 16 + lm;          // o-local
                size_t pos = ((size_t)b * N_ + n0 + row) * OUT_ + o0 + col;
                float v = mx[i][j][g];
                v = fmaxf(v, (float)HWN[pos]);
                v = fmaxf(v, (float)HWN[slab + pos]);
                v = fmaxf(v, (float)HWN[2 * slab + pos]);
                out[pos] = v + bias[(size_t)(n0 + row) * OUT_ + o0 + col];
            }
}

// ======================= round-1 fallback path (ws too small) ===========================
__global__ void cbias_kernel(const float* __restrict__ W, const float* __restrict__ We,
                             float* __restrict__ c) {
    int idx = blockIdx.x * 256 + threadIdx.x;
    if (idx >= NADJ_ * OUT_) return;
    int r = idx / OUT_, o = idx % OUT_;
    const float* Wr = W + (size_t)r * (F_ + REL_) * OUT_;
    float s = 0.f;
#pragma unroll
    for (int d = 0; d < REL_; ++d) s += We[r * REL_ + d] * Wr[(F_ + d) * OUT_ + o];
    c[idx] = s;
}

__global__ __launch_bounds__(256) void hw_kernel(const float* __restrict__ feat,
                                                 const float* __restrict__ W,
                                                 const float* __restrict__ cb,
                                                 _Float16* __restrict__ HWb) {
    __shared__ _Float16 As[64][32];
    __shared__ _Float16 Bs[64][32];
    const int mt = blockIdx.x, ct = blockIdx.y;
    const int tid = threadIdx.x, wave = tid >> 6, lane = tid & 63;
    const int r = (ct * 64) / OUT_;
    const int o0 = (ct * 64) % OUT_;
    const float* Bg = W + (size_t)r * (F_ + REL_) * OUT_ + o0;
    const int m0 = mt * 64;
    const int lm = lane & 15, q = lane >> 4;
    f32x4 acc[4] = {};
    for (int k0 = 0; k0 < F_; k0 += 32) {
        {
            int seg = (tid & 3) * 8, m = tid >> 2;
            const float* src = feat + (size_t)(m0 + m) * F_ + k0 + seg;
#pragma unroll
            for (int j = 0; j < 8; ++j) As[m][seg + j] = (_Float16)src[j];
        }
        {
            int kk = tid >> 3, ns = (tid & 7) * 8;
            const float* src = Bg + (size_t)(k0 + kk) * OUT_ + ns;
#pragma unroll
            for (int j = 0; j < 8; ++j) Bs[ns + j][kk] = (_Float16)src[j];
        }
        __syncthreads();
        f16x8 a = *(const f16x8*)&As[wave * 16 + lm][q * 8];
#pragma unroll
        for (int c4 = 0; c4 < 4; ++c4) {
            f16x8 b = *(const f16x8*)&Bs[c4 * 16 + lm][q * 8];
            acc[c4] = __builtin_amdgcn_mfma_f32_16x16x32_f16(a, b, acc[c4], 0, 0, 0);
        }
        __syncthreads();
    }
#pragma unroll
    for (int c4 = 0; c4 < 4; ++c4)
#pragma unroll
        for (int g = 0; g < 4; ++g) {
            int row = wave * 16 + (lane >> 4) * 4 + g;
            int col = c4 * 16 + lm;
            float v = acc[c4][g] + cb[r * OUT_ + o0 + col];
            HWb[((size_t)r * B_ * N_ + m0 + row) * OUT_ + o0 + col] = (_Float16)v;
        }
}

__global__ __launch_bounds__(256) void agg_kernel(const float* __restrict__ A1,
                                                  const float* __restrict__ A2,
                                                  const _Float16* __restrict__ HWb,
                                                  const float* __restrict__ bias,
                                                  float* __restrict__ out) {
    __shared__ _Float16 As[64][32];
    __shared__ _Float16 Bs[64][32];
    const int b = blockIdx.z, nt = blockIdx.y, ot = blockIdx.x;
    const int tid = threadIdx.x, wave = tid >> 6, lane = tid & 63;
    const int n0 = nt * 64, o0 = ot * 64;
    const int lm = lane & 15, q = lane >> 4;
    const size_t rstride = (size_t)B_ * N_ * OUT_;
    f32x4 mx[4];
#pragma unroll
    for (int i = 0; i < 4; ++i) mx[i] = f32x4{-1e30f, -1e30f, -1e30f, -1e30f};
#pragma unroll 1
    for (int rr = 0; rr < 4; ++rr) {
        const float* Ag = ((rr & 1) ? A2 : A1) + (size_t)b * N_ * N_;
        const bool tr = (rr >= 2);
        const int r = (rr < 2) ? rr : rr + 1;
        const _Float16* Bg = HWb + (size_t)r * rstride + (size_t)b * N_ * OUT_ + o0;
        f32x4 acc[4] = {};
        for (int k0 = 0; k0 < N_; k0 += 32) {
            if (!tr) {
                int seg = (tid & 3) * 8, m = tid >> 2;
                const float* src = Ag + (size_t)(n0 + m) * N_ + k0 + seg;
#pragma unroll
                for (int j = 0; j < 8; ++j) As[m][seg + j] = (_Float16)src[j];
            } else {
                int kk = tid >> 3, ms = (tid & 7) * 8;
                const float* src = Ag + (size_t)(k0 + kk) * N_ + n0 + ms;
#pragma unroll
                for (int j = 0; j < 8; ++j) As[ms + j][kk] = (_Float16)src[j];
            }
            {
                int kk = tid >> 3, ns = (tid & 7) * 8;
                const _Float16* src = Bg + (size_t)(k0 + kk) * OUT_ + ns;
#pragma unroll
                for (int j = 0; j < 8; ++j) Bs[ns + j][kk] = src[j];
            }
            __syncthreads();
            f16x8 a = *(const f16x8*)&As[wave * 16 + lm][q * 8];
#pragma unroll
            for (int c4 = 0; c4 < 4; ++c4) {
                f16x8 bb = *(const f16x8*)&Bs[c4 * 16 + lm][q * 8];
                acc[c4] = __builtin_amdgcn_mfma_f32_16x16x32_f16(a, bb, acc[c4], 0, 0, 0);
            }
            __syncthreads();
        }
#pragma unroll
        for (int c4 = 0; c4 < 4; ++c4)
#pragma unroll
            for (int g = 0; g < 4; ++g) mx[c4][g] = fmaxf(mx[c4][g], acc[c4][g]);
    }
#pragma unroll
    for (int c4 = 0; c4 < 4; ++c4)
#pragma unroll
        for (int g = 0; g < 4; ++g) {
            int row = wave * 16 + (lane >> 4) * 4 + g;
            int col = c4 * 16 + lm;
            size_t pos = ((size_t)b * N_ + n0 + row) * OUT_ + o0 + col;
            float v = mx[c4][g];
            v = fmaxf(v, (float)HWb[2 * rstride + pos]);
            v = fmaxf(v, (float)HWb[5 * rstride + pos]);
            v = fmaxf(v, (float)HWb[6 * rstride + pos]);
            out[pos] = v + bias[((size_t)(n0 + row)) * OUT_ + o0 + col];
        }
}

// ========================================================================================
extern "C" void kernel_launch(void* const* d_in, const int* in_sizes, int n_in,
                              void* d_out, int out_size, void* d_ws, size_t ws_size,
                              hipStream_t stream) {
    const float* feat = (const float*)d_in[0];
    const float* A1   = (const float*)d_in[1];
    const float* A2   = (const float*)d_in[2];
    const float* W    = (const float*)d_in[3];
    const float* We   = (const float*)d_in[4];
    const float* bias = (const float*)d_in[5];
    float* out = (float*)d_out;

    // fast-path ws layout (bytes)
    const size_t OFF_CB   = 0;          //   8 KB
    const size_t OFF_WT   = 8192;       // 896 KB
    const size_t OFF_FE   = 1048576;    //   4 MB
    const size_t OFF_AF   = 5242880;    //  64 MB
    const size_t OFF_HWT  = 72351744;   //  16 MB
    const size_t OFF_HWN  = 89128960;   //  12 MB
    const size_t WS_NEEDED = 101711872;

    if (ws_size >= WS_NEEDED) {
        float*    cbp = (float*)((char*)d_ws + OFF_CB);
        _Float16* WTp = (_Float16*)((char*)d_ws + OFF_WT);
        _Float16* Fe  = (_Float16*)((char*)d_ws + OFF_FE);
        _Float16* Af  = (_Float16*)((char*)d_ws + OFF_AF);
        _Float16* HWT = (_Float16*)((char*)d_ws + OFF_HWT);
        _Float16* HWN = (_Float16*)((char*)d_ws + OFF_HWN);

        prep_kernel<<<2823, 256, 0, stream>>>(W, We, feat, cbp, WTp, Fe);
        convhw_kernel<<<4992, 256, 0, stream>>>(A1, A2, Fe, WTp, cbp, Af, HWT, HWN);
        p2max_kernel<<<256, 256, 0, stream>>>(Af, HWT, HWN, bias, out);
    } else {
        // round-1 fallback
        float* cb = (float*)d_ws;
        _Float16* HWb = (_Float16*)((char*)d_ws + 8192);
        cbias_kernel<<<7, 256, 0, stream>>>(W, We, cb);
        hw_kernel<<<dim3(128, 28), 256, 0, stream>>>(feat, W, cb, HWb);
        agg_kernel<<<dim3(4, 16, 8), 256, 0, stream>>>(A1, A2, HWb, bias, out);
    }
}

// Round 7
// 176.716 us; speedup vs baseline: 1.1198x; 1.1198x over previous
//
#include <hip/hip_runtime.h>
#include <hip/hip_bf16.h>

#define B_ 8
#define N_ 1024
#define F_ 256
#define OUT_ 256
#define REL_ 16
#define NADJ_ 7

typedef __attribute__((ext_vector_type(8))) _Float16 f16x8;
typedef __attribute__((ext_vector_type(4))) float f32x4;

__device__ __forceinline__ void gll16(const _Float16* g, _Float16* l) {
    __builtin_amdgcn_global_load_lds(
        (const __attribute__((address_space(1))) void*)g,
        (__attribute__((address_space(3))) void*)l, 16, 0, 0);
}

// perm order: rr 0..3 = r{0,1,3,4} (real adjacency), 4..6 = r{2,5,6} (identity adjacency)
__constant__ const int c_perm[7] = {0, 1, 3, 4, 2, 5, 6};

// ---------------- prep: cbias (blocks 0..6) | transW (7..1798) | cvt feat (1799..2822) ---
__global__ __launch_bounds__(256) void prep_kernel(const float* __restrict__ W,
                                                   const float* __restrict__ We,
                                                   const float* __restrict__ feat,
                                                   float* __restrict__ cb,
                                                   _Float16* __restrict__ WTp,
                                                   _Float16* __restrict__ Fe) {
    int bid = blockIdx.x, tid = threadIdx.x;
    if (bid < 7) {
        int idx = bid * 256 + tid;
        int j = idx / OUT_, o = idx % OUT_;
        int r = c_perm[j];
        const float* Wr = W + (size_t)r * (F_ + REL_) * OUT_;
        float s = 0.f;
#pragma unroll
        for (int d = 0; d < REL_; ++d) s += We[r * REL_ + d] * Wr[(F_ + d) * OUT_ + o];
        cb[idx] = s;
    } else if (bid < 1799) {
        int idx = (bid - 7) * 256 + tid;  // 7*65536 total
        int j = idx >> 16, rem = idx & 65535, o = rem >> 8, f = rem & 255;
        int r = c_perm[j];
        WTp[idx] = (_Float16)W[((size_t)r * (F_ + REL_) + f) * OUT_ + o];
    } else {
        int i = (bid - 1799) * 256 + tid;  // 262144 groups of 8
        size_t base = (size_t)i * 8;
        float4 a = *(const float4*)(feat + base);
        float4 b = *(const float4*)(feat + base + 4);
        f16x8 v = {(_Float16)a.x, (_Float16)a.y, (_Float16)a.z, (_Float16)a.w,
                   (_Float16)b.x, (_Float16)b.y, (_Float16)b.z, (_Float16)b.w};
        *(f16x8*)(Fe + base) = v;
    }
}

// ======= merged: blocks [0,896) = hw7 GEMMs (MFMA) | [896,4992) = convA (memory) =======
// hw7 first so its MFMA overlaps convA's memory streaming on co-resident CUs.
__global__ __launch_bounds__(256) void convhw_kernel(const float* __restrict__ A1,
                                                     const float* __restrict__ A2,
                                                     const _Float16* __restrict__ Fe,
                                                     const _Float16* __restrict__ WTp,
                                                     const float* __restrict__ cb,
                                                     _Float16* __restrict__ Af,
                                                     _Float16* __restrict__ HWT,
                                                     _Float16* __restrict__ HWN) {
    __shared__ _Float16 S[8192];  // hw7: As=S[0..4096), Bs=S[4096..); convA: T=S[0..4096)
    const int bid = blockIdx.x, tid = threadIdx.x;
    if (bid < 896) {
        // hw7: z<4: HWT[z][o][m] = (Fe @ W[z])^T + cb ; z>=4: HWN[z-4][m][o] = Fe @ W[z] + cb
        const int z = bid / 128, rem = bid % 128, bx = rem & 63, by = rem >> 6;
        const bool tr = (z < 4);
        const _Float16* A  = tr ? (WTp + (size_t)z * 65536) : Fe;
        const _Float16* Bt = tr ? Fe : (WTp + (size_t)z * 65536);
        const int m0 = (tr ? by : bx) * 128;
        const int n0 = (tr ? bx : by) * 128;
        _Float16* As = S;
        _Float16* Bs = S + 4096;
        const int wave = tid >> 6, lane = tid & 63, lm = lane & 15, q = lane >> 4;
        const int wr = (wave >> 1) * 64, wc = (wave & 1) * 64;
        const int srow = tid >> 2, sk = (tid & 3) * 8;
        const _Float16* ga0 = A + (size_t)(m0 + srow) * F_ + sk;
        const _Float16* ga1 = ga0 + (size_t)64 * F_;
        const _Float16* gb0 = Bt + (size_t)(n0 + srow) * F_ + sk;
        const _Float16* gb1 = gb0 + (size_t)64 * F_;
        _Float16* la0 = As + tid * 8;
        _Float16* la1 = As + 2048 + tid * 8;
        _Float16* lb0 = Bs + tid * 8;
        _Float16* lb1 = Bs + 2048 + tid * 8;

        f32x4 acc[4][4] = {};
        for (int k0 = 0; k0 < F_; k0 += 32) {
            gll16(ga0 + k0, la0);
            gll16(ga1 + k0, la1);
            gll16(gb0 + k0, lb0);
            gll16(gb1 + k0, lb1);
            __syncthreads();
            f16x8 af[4], bf[4];
#pragma unroll
            for (int i = 0; i < 4; ++i) af[i] = *(const f16x8*)(As + (wr + i * 16 + lm) * 32 + q * 8);
#pragma unroll
            for (int j = 0; j < 4; ++j) bf[j] = *(const f16x8*)(Bs + (wc + j * 16 + lm) * 32 + q * 8);
#pragma unroll
            for (int i = 0; i < 4; ++i)
#pragma unroll
                for (int j = 0; j < 4; ++j)
                    acc[i][j] = __builtin_amdgcn_mfma_f32_16x16x32_f16(af[i], bf[j], acc[i][j], 0, 0, 0);
            __syncthreads();
        }
        const float* cbz = cb + (size_t)z * 256;
        if (tr) {
            _Float16* C = HWT + (size_t)z * ((size_t)256 * 8192);
#pragma unroll
            for (int i = 0; i < 4; ++i)
#pragma unroll
                for (int j = 0; j < 4; ++j)
#pragma unroll
                    for (int g = 0; g < 4; ++g) {
                        int row = wr + i * 16 + q * 4 + g;   // o
                        int col = wc + j * 16 + lm;          // m
                        float v = acc[i][j][g] + cbz[m0 + row];
                        C[(size_t)(m0 + row) * 8192 + (n0 + col)] = (_Float16)v;
                    }
        } else {
            _Float16* C = HWN + (size_t)(z - 4) * ((size_t)8192 * 256);
#pragma unroll
            for (int i = 0; i < 4; ++i)
#pragma unroll
                for (int j = 0; j < 4; ++j)
#pragma unroll
                    for (int g = 0; g < 4; ++g) {
                        int row = wr + i * 16 + q * 4 + g;   // m
                        int col = wc + j * 16 + lm;          // o
                        float v = acc[i][j][g] + cbz[n0 + col];
                        C[(size_t)(m0 + row) * 256 + (n0 + col)] = (_Float16)v;
                    }
        }
    } else {
        // convA: A1/A2 -> f16 straight + transposed slabs, XOR-swizzled LDS transpose
        _Float16* T = S;
        const int cbid = bid - 896;
        int z = cbid >> 8, s = z >> 3, b = z & 7;
        const float* src = (s ? A2 : A1) + (size_t)b * N_ * N_;
        int k0 = (cbid & 15) * 64, n0 = ((cbid >> 4) & 15) * 64;
        int r = tid >> 2, cs = (tid & 3) * 16;
        const float* sp = src + (size_t)(k0 + r) * N_ + n0 + cs;
        _Float16 v[16];
#pragma unroll
        for (int j = 0; j < 16; j += 4) {
            float4 f = *(const float4*)(sp + j);
            v[j] = (_Float16)f.x; v[j + 1] = (_Float16)f.y;
            v[j + 2] = (_Float16)f.z; v[j + 3] = (_Float16)f.w;
        }
        const size_t slab = (size_t)8 * N_ * N_;
        {   // straight: Af[s][b][k0+r][n0+cs..+16]
            _Float16* dst = Af + (size_t)s * slab + (size_t)b * N_ * N_ + (size_t)(k0 + r) * N_ + n0 + cs;
            f16x8 p0 = {v[0], v[1], v[2], v[3], v[4], v[5], v[6], v[7]};
            f16x8 p1 = {v[8], v[9], v[10], v[11], v[12], v[13], v[14], v[15]};
            *(f16x8*)dst = p0;
            *(f16x8*)(dst + 8) = p1;
        }
#pragma unroll
        for (int j = 0; j < 16; ++j) {
            int n = cs + j;
            int sw = ((n ^ (n >> 3)) & 7) << 3;
            T[n * 64 + (r ^ sw)] = v[j];
        }
        __syncthreads();
        {
            int n = tid >> 2, i2 = (tid & 3) * 16;
            int sw = ((n ^ (n >> 3)) & 7) << 3;
            f16x8 q0 = *(const f16x8*)&T[n * 64 + (i2 ^ sw)];
            f16x8 q1 = *(const f16x8*)&T[n * 64 + ((i2 + 8) ^ sw)];
            _Float16* dt = Af + (size_t)(2 + s) * slab + (size_t)b * N_ * N_ + (size_t)(n0 + n) * N_ + k0 + i2;
            *(f16x8*)dt = q0;
            *(f16x8*)(dt + 8) = q1;
        }
    }
}

// ======= phase2: AHW[rr][b][n][o] = Af[rr][b] @ HWT[rr][:, b*1024:+1024]^T =======
// 1D grid 512, 128x128 tiles, 2 blocks/CU. XCD-pair swizzle: blocks d and d+8 share
// (rr,b,mtile), differ in o-tile -> same XCD under round-robin -> A-tile L2 reuse.
__global__ __launch_bounds__(256) void p2_kernel(const _Float16* __restrict__ Af,
                                                 const _Float16* __restrict__ HWT,
                                                 _Float16* __restrict__ AHW) {
    __shared__ _Float16 As[128 * 32];
    __shared__ _Float16 Bs[128 * 32];
    const int d = blockIdx.x;
    const int member = (d >> 3) & 1;            // o-tile
    const int p = (d & 7) | ((d >> 4) << 3);    // [0,256)
    const int mt = p & 7, zz = p >> 3;          // mt: m-tile, zz = rr*8+b
    const int rr = zz >> 3, b = zz & 7;
    const _Float16* A  = Af + (size_t)rr * (8 * 1048576) + (size_t)b * 1048576;
    const _Float16* Bt = HWT + (size_t)rr * (256 * 8192) + (size_t)b * 1024;
    _Float16* C = AHW + (size_t)rr * (8 * 262144) + (size_t)b * 262144;
    const int m0 = mt * 128, n0 = member * 128;
    const int tid = threadIdx.x;
    const int wave = tid >> 6, lane = tid & 63, lm = lane & 15, q = lane >> 4;
    const int wr = (wave >> 1) * 64, wc = (wave & 1) * 64;
    const int srow = tid >> 2, sk = (tid & 3) * 8;
    const _Float16* ga0 = A + (size_t)(m0 + srow) * N_ + sk;
    const _Float16* ga1 = ga0 + (size_t)64 * N_;
    const _Float16* gb0 = Bt + (size_t)(n0 + srow) * 8192 + sk;
    const _Float16* gb1 = gb0 + (size_t)64 * 8192;
    _Float16* la0 = As + tid * 8;
    _Float16* la1 = As + 2048 + tid * 8;
    _Float16* lb0 = Bs + tid * 8;
    _Float16* lb1 = Bs + 2048 + tid * 8;

    f32x4 acc[4][4] = {};
    for (int k0 = 0; k0 < N_; k0 += 32) {
        gll16(ga0 + k0, la0);
        gll16(ga1 + k0, la1);
        gll16(gb0 + k0, lb0);
        gll16(gb1 + k0, lb1);
        __syncthreads();
        f16x8 af[4], bf[4];
#pragma unroll
        for (int i = 0; i < 4; ++i) af[i] = *(const f16x8*)(As + (wr + i * 16 + lm) * 32 + q * 8);
#pragma unroll
        for (int j = 0; j < 4; ++j) bf[j] = *(const f16x8*)(Bs + (wc + j * 16 + lm) * 32 + q * 8);
#pragma unroll
        for (int i = 0; i < 4; ++i)
#pragma unroll
            for (int j = 0; j < 4; ++j)
                acc[i][j] = __builtin_amdgcn_mfma_f32_16x16x32_f16(af[i], bf[j], acc[i][j], 0, 0, 0);
        __syncthreads();
    }
#pragma unroll
    for (int i = 0; i < 4; ++i)
#pragma unroll
        for (int j = 0; j < 4; ++j)
#pragma unroll
            for (int g = 0; g < 4; ++g) {
                int row = wr + i * 16 + q * 4 + g;
                int col = wc + j * 16 + lm;
                C[(size_t)(m0 + row) * 256 + (n0 + col)] = (_Float16)acc[i][j][g];
            }
}

// ======= final: out = max(AHW[0..3], HWN[0..2]) + bias =======
__global__ __launch_bounds__(256) void max_kernel(const _Float16* __restrict__ AHW,
                                                  const _Float16* __restrict__ HWN,
                                                  const float* __restrict__ bias,
                                                  float* __restrict__ out) {
    size_t i = ((size_t)blockIdx.x * 256 + threadIdx.x) * 8;
    const size_t slab = (size_t)B_ * N_ * OUT_;
    float m[8];
    f16x8 v = *(const f16x8*)(AHW + i);
#pragma unroll
    for (int e = 0; e < 8; ++e) m[e] = (float)v[e];
#pragma unroll
    for (int rr = 1; rr < 4; ++rr) {
        f16x8 w = *(const f16x8*)(AHW + rr * slab + i);
#pragma unroll
        for (int e = 0; e < 8; ++e) m[e] = fmaxf(m[e], (float)w[e]);
    }
#pragma unroll
    for (int j = 0; j < 3; ++j) {
        f16x8 w = *(const f16x8*)(HWN + j * slab + i);
#pragma unroll
        for (int e = 0; e < 8; ++e) m[e] = fmaxf(m[e], (float)w[e]);
    }
    size_t bidx = i & ((size_t)N_ * OUT_ - 1);
    float4 b0 = *(const float4*)(bias + bidx);
    float4 b1 = *(const float4*)(bias + bidx + 4);
    float4 o0 = {m[0] + b0.x, m[1] + b0.y, m[2] + b0.z, m[3] + b0.w};
    float4 o1 = {m[4] + b1.x, m[5] + b1.y, m[6] + b1.z, m[7] + b1.w};
    *(float4*)(out + i) = o0;
    *(float4*)(out + i + 4) = o1;
}

// ======================= round-1 fallback path (ws too small) ===========================
__global__ void cbias_kernel(const float* __restrict__ W, const float* __restrict__ We,
                             float* __restrict__ c) {
    int idx = blockIdx.x * 256 + threadIdx.x;
    if (idx >= NADJ_ * OUT_) return;
    int r = idx / OUT_, o = idx % OUT_;
    const float* Wr = W + (size_t)r * (F_ + REL_) * OUT_;
    float s = 0.f;
#pragma unroll
    for (int d = 0; d < REL_; ++d) s += We[r * REL_ + d] * Wr[(F_ + d) * OUT_ + o];
    c[idx] = s;
}

__global__ __launch_bounds__(256) void hw_kernel(const float* __restrict__ feat,
                                                 const float* __restrict__ W,
                                                 const float* __restrict__ cb,
                                                 _Float16* __restrict__ HWb) {
    __shared__ _Float16 As[64][32];
    __shared__ _Float16 Bs[64][32];
    const int mt = blockIdx.x, ct = blockIdx.y;
    const int tid = threadIdx.x, wave = tid >> 6, lane = tid & 63;
    const int r = (ct * 64) / OUT_;
    const int o0 = (ct * 64) % OUT_;
    const float* Bg = W + (size_t)r * (F_ + REL_) * OUT_ + o0;
    const int m0 = mt * 64;
    const int lm = lane & 15, q = lane >> 4;
    f32x4 acc[4] = {};
    for (int k0 = 0; k0 < F_; k0 += 32) {
        {
            int seg = (tid & 3) * 8, m = tid >> 2;
            const float* src = feat + (size_t)(m0 + m) * F_ + k0 + seg;
#pragma unroll
            for (int j = 0; j < 8; ++j) As[m][seg + j] = (_Float16)src[j];
        }
        {
            int kk = tid >> 3, ns = (tid & 7) * 8;
            const float* src = Bg + (size_t)(k0 + kk) * OUT_ + ns;
#pragma unroll
            for (int j = 0; j < 8; ++j) Bs[ns + j][kk] = (_Float16)src[j];
        }
        __syncthreads();
        f16x8 a = *(const f16x8*)&As[wave * 16 + lm][q * 8];
#pragma unroll
        for (int c4 = 0; c4 < 4; ++c4) {
            f16x8 b = *(const f16x8*)&Bs[c4 * 16 + lm][q * 8];
            acc[c4] = __builtin_amdgcn_mfma_f32_16x16x32_f16(a, b, acc[c4], 0, 0, 0);
        }
        __syncthreads();
    }
#pragma unroll
    for (int c4 = 0; c4 < 4; ++c4)
#pragma unroll
        for (int g = 0; g < 4; ++g) {
            int row = wave * 16 + (lane >> 4) * 4 + g;
            int col = c4 * 16 + lm;
            float v = acc[c4][g] + cb[r * OUT_ + o0 + col];
            HWb[((size_t)r * B_ * N_ + m0 + row) * OUT_ + o0 + col] = (_Float16)v;
        }
}

__global__ __launch_bounds__(256) void agg_kernel(const float* __restrict__ A1,
                                                  const float* __restrict__ A2,
                                                  const _Float16* __restrict__ HWb,
                                                  const float* __restrict__ bias,
                                                  float* __restrict__ out) {
    __shared__ _Float16 As[64][32];
    __shared__ _Float16 Bs[64][32];
    const int b = blockIdx.z, nt = blockIdx.y, ot = blockIdx.x;
    const int tid = threadIdx.x, wave = tid >> 6, lane = tid & 63;
    const int n0 = nt * 64, o0 = ot * 64;
    const int lm = lane & 15, q = lane >> 4;
    const size_t rstride = (size_t)B_ * N_ * OUT_;
    f32x4 mx[4];
#pragma unroll
    for (int i = 0; i < 4; ++i) mx[i] = f32x4{-1e30f, -1e30f, -1e30f, -1e30f};
#pragma unroll 1
    for (int rr = 0; rr < 4; ++rr) {
        const float* Ag = ((rr & 1) ? A2 : A1) + (size_t)b * N_ * N_;
        const bool tr = (rr >= 2);
        const int r = (rr < 2) ? rr : rr + 1;
        const _Float16* Bg = HWb + (size_t)r * rstride + (size_t)b * N_ * OUT_ + o0;
        f32x4 acc[4] = {};
        for (int k0 = 0; k0 < N_; k0 += 32) {
            if (!tr) {
                int seg = (tid & 3) * 8, m = tid >> 2;
                const float* src = Ag + (size_t)(n0 + m) * N_ + k0 + seg;
#pragma unroll
                for (int j = 0; j < 8; ++j) As[m][seg + j] = (_Float16)src[j];
            } else {
                int kk = tid >> 3, ms = (tid & 7) * 8;
                const float* src = Ag + (size_t)(k0 + kk) * N_ + n0 + ms;
#pragma unroll
                for (int j = 0; j < 8; ++j) As[ms + j][kk] = (_Float16)src[j];
            }
            {
                int kk = tid >> 3, ns = (tid & 7) * 8;
                const _Float16* src = Bg + (size_t)(k0 + kk) * OUT_ + ns;
#pragma unroll
                for (int j = 0; j < 8; ++j) Bs[ns + j][kk] = src[j];
            }
            __syncthreads();
            f16x8 a = *(const f16x8*)&As[wave * 16 + lm][q * 8];
#pragma unroll
            for (int c4 = 0; c4 < 4; ++c4) {
                f16x8 bb = *(const f16x8*)&Bs[c4 * 16 + lm][q * 8];
                acc[c4] = __builtin_amdgcn_mfma_f32_16x16x32_f16(a, bb, acc[c4], 0, 0, 0);
            }
            __syncthreads();
        }
#pragma unroll
        for (int c4 = 0; c4 < 4; ++c4)
#pragma unroll
            for (int g = 0; g < 4; ++g) mx[c4][g] = fmaxf(mx[c4][g], acc[c4][g]);
    }
#pragma unroll
    for (int c4 = 0; c4 < 4; ++c4)
#pragma unroll
        for (int g = 0; g < 4; ++g) {
            int row = wave * 16 + (lane >> 4) * 4 + g;
            int col = c4 * 16 + lm;
            size_t pos = ((size_t)b * N_ + n0 + row) * OUT_ + o0 + col;
            float v = mx[c4][g];
            v = fmaxf(v, (float)HWb[2 * rstride + pos]);
            v = fmaxf(v, (float)HWb[5 * rstride + pos]);
            v = fmaxf(v, (float)HWb[6 * rstride + pos]);
            out[pos] = v + bias[((size_t)(n0 + row)) * OUT_ + o0 + col];
        }
}

// ========================================================================================
extern "C" void kernel_launch(void* const* d_in, const int* in_sizes, int n_in,
                              void* d_out, int out_size, void* d_ws, size_t ws_size,
                              hipStream_t stream) {
    const float* feat = (const float*)d_in[0];
    const float* A1   = (const float*)d_in[1];
    const float* A2   = (const float*)d_in[2];
    const float* W    = (const float*)d_in[3];
    const float* We   = (const float*)d_in[4];
    const float* bias = (const float*)d_in[5];
    float* out = (float*)d_out;

    // fast-path ws layout (bytes)
    const size_t OFF_CB   = 0;          //   8 KB
    const size_t OFF_WT   = 8192;       // 896 KB
    const size_t OFF_FE   = 1048576;    //   4 MB
    const size_t OFF_AF   = 5242880;    //  64 MB
    const size_t OFF_HWT  = 72351744;   //  16 MB
    const size_t OFF_HWN  = 89128960;   //  12 MB
    const size_t OFF_AHW  = 101711872;  //  16 MB
    const size_t WS_NEEDED = 118489088;

    if (ws_size >= WS_NEEDED) {
        float*    cbp = (float*)((char*)d_ws + OFF_CB);
        _Float16* WTp = (_Float16*)((char*)d_ws + OFF_WT);
        _Float16* Fe  = (_Float16*)((char*)d_ws + OFF_FE);
        _Float16* Af  = (_Float16*)((char*)d_ws + OFF_AF);
        _Float16* HWT = (_Float16*)((char*)d_ws + OFF_HWT);
        _Float16* HWN = (_Float16*)((char*)d_ws + OFF_HWN);
        _Float16* AHW = (_Float16*)((char*)d_ws + OFF_AHW);

        prep_kernel<<<2823, 256, 0, stream>>>(W, We, feat, cbp, WTp, Fe);
        convhw_kernel<<<4992, 256, 0, stream>>>(A1, A2, Fe, WTp, cbp, Af, HWT, HWN);
        p2_kernel<<<512, 256, 0, stream>>>(Af, HWT, AHW);
        max_kernel<<<1024, 256, 0, stream>>>(AHW, HWN, bias, out);
    } else {
        // round-1 fallback
        float* cb = (float*)d_ws;
        _Float16* HWb = (_Float16*)((char*)d_ws + 8192);
        cbias_kernel<<<7, 256, 0, stream>>>(W, We, cb);
        hw_kernel<<<dim3(128, 28), 256, 0, stream>>>(feat, W, cb, HWb);
        agg_kernel<<<dim3(4, 16, 8), 256, 0, stream>>>(A1, A2, HWb, bias, out);
    }
}

// Round 8
// 176.365 us; speedup vs baseline: 1.1220x; 1.0020x over previous
//
#include <hip/hip_runtime.h>
#include <hip/hip_bf16.h>

#define B_ 8
#define N_ 1024
#define F_ 256
#define OUT_ 256
#define REL_ 16
#define NADJ_ 7

typedef __attribute__((ext_vector_type(8))) _Float16 f16x8;
typedef __attribute__((ext_vector_type(4))) float f32x4;

__device__ __forceinline__ void gll16(const _Float16* g, _Float16* l) {
    __builtin_amdgcn_global_load_lds(
        (const __attribute__((address_space(1))) void*)g,
        (__attribute__((address_space(3))) void*)l, 16, 0, 0);
}

// perm order: rr 0..3 = r{0,1,3,4} (real adjacency), 4..6 = r{2,5,6} (identity adjacency)
__constant__ const int c_perm[7] = {0, 1, 3, 4, 2, 5, 6};

// ---------------- prep: cbias (blocks 0..6) | transW (7..1798) | cvt feat (1799..2822) ---
__global__ __launch_bounds__(256) void prep_kernel(const float* __restrict__ W,
                                                   const float* __restrict__ We,
                                                   const float* __restrict__ feat,
                                                   float* __restrict__ cb,
                                                   _Float16* __restrict__ WTp,
                                                   _Float16* __restrict__ Fe) {
    int bid = blockIdx.x, tid = threadIdx.x;
    if (bid < 7) {
        int idx = bid * 256 + tid;
        int j = idx / OUT_, o = idx % OUT_;
        int r = c_perm[j];
        const float* Wr = W + (size_t)r * (F_ + REL_) * OUT_;
        float s = 0.f;
#pragma unroll
        for (int d = 0; d < REL_; ++d) s += We[r * REL_ + d] * Wr[(F_ + d) * OUT_ + o];
        cb[idx] = s;
    } else if (bid < 1799) {
        int idx = (bid - 7) * 256 + tid;  // 7*65536 total
        int j = idx >> 16, rem = idx & 65535, o = rem >> 8, f = rem & 255;
        int r = c_perm[j];
        WTp[idx] = (_Float16)W[((size_t)r * (F_ + REL_) + f) * OUT_ + o];
    } else {
        int i = (bid - 1799) * 256 + tid;  // 262144 groups of 8
        size_t base = (size_t)i * 8;
        float4 a = *(const float4*)(feat + base);
        float4 b = *(const float4*)(feat + base + 4);
        f16x8 v = {(_Float16)a.x, (_Float16)a.y, (_Float16)a.z, (_Float16)a.w,
                   (_Float16)b.x, (_Float16)b.y, (_Float16)b.z, (_Float16)b.w};
        *(f16x8*)(Fe + base) = v;
    }
}

// ======= merged: blocks [0,896) = hw7 GEMMs (MFMA) | [896,4992) = convA (transpose only)
// Af holds ONLY A1^T, A2^T (2 slabs x 16 MB f16). Straight A is consumed fp32 by p2.
__global__ __launch_bounds__(256) void convhw_kernel(const float* __restrict__ A1,
                                                     const float* __restrict__ A2,
                                                     const _Float16* __restrict__ Fe,
                                                     const _Float16* __restrict__ WTp,
                                                     const float* __restrict__ cb,
                                                     _Float16* __restrict__ Af,
                                                     _Float16* __restrict__ HWT,
                                                     _Float16* __restrict__ HWN) {
    __shared__ _Float16 S[8192];  // hw7: As=S[0..4096), Bs=S[4096..); convA: T=S[0..4096)
    const int bid = blockIdx.x, tid = threadIdx.x;
    if (bid < 896) {
        // hw7: z<4: HWT[z][o][m] = (Fe @ W[z])^T + cb ; z>=4: HWN[z-4][m][o] = Fe @ W[z] + cb
        const int z = bid / 128, rem = bid % 128, bx = rem & 63, by = rem >> 6;
        const bool tr = (z < 4);
        const _Float16* A  = tr ? (WTp + (size_t)z * 65536) : Fe;
        const _Float16* Bt = tr ? Fe : (WTp + (size_t)z * 65536);
        const int m0 = (tr ? by : bx) * 128;
        const int n0 = (tr ? bx : by) * 128;
        _Float16* As = S;
        _Float16* Bs = S + 4096;
        const int wave = tid >> 6, lane = tid & 63, lm = lane & 15, q = lane >> 4;
        const int wr = (wave >> 1) * 64, wc = (wave & 1) * 64;
        const int srow = tid >> 2, sk = (tid & 3) * 8;
        const _Float16* ga0 = A + (size_t)(m0 + srow) * F_ + sk;
        const _Float16* ga1 = ga0 + (size_t)64 * F_;
        const _Float16* gb0 = Bt + (size_t)(n0 + srow) * F_ + sk;
        const _Float16* gb1 = gb0 + (size_t)64 * F_;
        _Float16* la0 = As + tid * 8;
        _Float16* la1 = As + 2048 + tid * 8;
        _Float16* lb0 = Bs + tid * 8;
        _Float16* lb1 = Bs + 2048 + tid * 8;

        f32x4 acc[4][4] = {};
        for (int k0 = 0; k0 < F_; k0 += 32) {
            gll16(ga0 + k0, la0);
            gll16(ga1 + k0, la1);
            gll16(gb0 + k0, lb0);
            gll16(gb1 + k0, lb1);
            __syncthreads();
            f16x8 af[4], bf[4];
#pragma unroll
            for (int i = 0; i < 4; ++i) af[i] = *(const f16x8*)(As + (wr + i * 16 + lm) * 32 + q * 8);
#pragma unroll
            for (int j = 0; j < 4; ++j) bf[j] = *(const f16x8*)(Bs + (wc + j * 16 + lm) * 32 + q * 8);
#pragma unroll
            for (int i = 0; i < 4; ++i)
#pragma unroll
                for (int j = 0; j < 4; ++j)
                    acc[i][j] = __builtin_amdgcn_mfma_f32_16x16x32_f16(af[i], bf[j], acc[i][j], 0, 0, 0);
            __syncthreads();
        }
        const float* cbz = cb + (size_t)z * 256;
        if (tr) {
            _Float16* C = HWT + (size_t)z * ((size_t)256 * 8192);
#pragma unroll
            for (int i = 0; i < 4; ++i)
#pragma unroll
                for (int j = 0; j < 4; ++j)
#pragma unroll
                    for (int g = 0; g < 4; ++g) {
                        int row = wr + i * 16 + q * 4 + g;   // o
                        int col = wc + j * 16 + lm;          // m
                        float v = acc[i][j][g] + cbz[m0 + row];
                        C[(size_t)(m0 + row) * 8192 + (n0 + col)] = (_Float16)v;
                    }
        } else {
            _Float16* C = HWN + (size_t)(z - 4) * ((size_t)8192 * 256);
#pragma unroll
            for (int i = 0; i < 4; ++i)
#pragma unroll
                for (int j = 0; j < 4; ++j)
#pragma unroll
                    for (int g = 0; g < 4; ++g) {
                        int row = wr + i * 16 + q * 4 + g;   // m
                        int col = wc + j * 16 + lm;          // o
                        float v = acc[i][j][g] + cbz[n0 + col];
                        C[(size_t)(m0 + row) * 256 + (n0 + col)] = (_Float16)v;
                    }
        }
    } else {
        // convA: A1/A2 -> f16 TRANSPOSED slabs only, XOR-swizzled LDS transpose
        _Float16* T = S;
        const int cbid = bid - 896;
        int z = cbid >> 8, s = z >> 3, b = z & 7;
        const float* src = (s ? A2 : A1) + (size_t)b * N_ * N_;
        int k0 = (cbid & 15) * 64, n0 = ((cbid >> 4) & 15) * 64;
        int r = tid >> 2, cs = (tid & 3) * 16;
        const float* sp = src + (size_t)(k0 + r) * N_ + n0 + cs;
        _Float16 v[16];
#pragma unroll
        for (int j = 0; j < 16; j += 4) {
            float4 f = *(const float4*)(sp + j);
            v[j] = (_Float16)f.x; v[j + 1] = (_Float16)f.y;
            v[j + 2] = (_Float16)f.z; v[j + 3] = (_Float16)f.w;
        }
        const size_t slab = (size_t)8 * N_ * N_;
#pragma unroll
        for (int j = 0; j < 16; ++j) {
            int n = cs + j;
            int sw = ((n ^ (n >> 3)) & 7) << 3;
            T[n * 64 + (r ^ sw)] = v[j];
        }
        __syncthreads();
        {
            int n = tid >> 2, i2 = (tid & 3) * 16;
            int sw = ((n ^ (n >> 3)) & 7) << 3;
            f16x8 q0 = *(const f16x8*)&T[n * 64 + (i2 ^ sw)];
            f16x8 q1 = *(const f16x8*)&T[n * 64 + ((i2 + 8) ^ sw)];
            _Float16* dt = Af + (size_t)s * slab + (size_t)b * N_ * N_ + (size_t)(n0 + n) * N_ + k0 + i2;
            *(f16x8*)dt = q0;
            *(f16x8*)(dt + 8) = q1;
        }
    }
}

// ======= phase2: AHW[rr][b][n][o] = A_rr[b] @ HWT[rr][:, b*1024:+1024]^T =======
// 1D grid 512, 128x128 tiles. rr<2: A staged directly from fp32 A1/A2 (row-coalesced,
// register-prefetch + cvt + ds_write, identical LDS layout to gll16). rr>=2: gll16 from Af^T.
__global__ __launch_bounds__(256) void p2_kernel(const float* __restrict__ A1,
                                                 const float* __restrict__ A2,
                                                 const _Float16* __restrict__ Af,
                                                 const _Float16* __restrict__ HWT,
                                                 _Float16* __restrict__ AHW) {
    __shared__ _Float16 As[128 * 32];
    __shared__ _Float16 Bs[128 * 32];
    const int d = blockIdx.x;
    const int member = (d >> 3) & 1;            // o-tile
    const int p = (d & 7) | ((d >> 4) << 3);    // [0,256)
    const int mt = p & 7, zz = p >> 3;          // mt: m-tile, zz = rr*8+b
    const int rr = zz >> 3, b = zz & 7;
    const _Float16* Bt = HWT + (size_t)rr * (256 * 8192) + (size_t)b * 1024;
    _Float16* C = AHW + (size_t)rr * (8 * 262144) + (size_t)b * 262144;
    const int m0 = mt * 128, n0 = member * 128;
    const int tid = threadIdx.x;
    const int wave = tid >> 6, lane = tid & 63, lm = lane & 15, q = lane >> 4;
    const int wr = (wave >> 1) * 64, wc = (wave & 1) * 64;
    const int srow = tid >> 2, sk = (tid & 3) * 8;
    const _Float16* gb0 = Bt + (size_t)(n0 + srow) * 8192 + sk;
    const _Float16* gb1 = gb0 + (size_t)64 * 8192;
    _Float16* la0 = As + tid * 8;
    _Float16* la1 = As + 2048 + tid * 8;
    _Float16* lb0 = Bs + tid * 8;
    _Float16* lb1 = Bs + 2048 + tid * 8;

    f32x4 acc[4][4] = {};
    if (rr < 2) {
        // direct fp32 staging with register prefetch
        const float* Ag0 = ((rr & 1) ? A2 : A1) + (size_t)b * N_ * N_
                           + (size_t)(m0 + srow) * N_ + sk;
        const float* Ag1 = Ag0 + (size_t)64 * N_;
        float4 pa0 = *(const float4*)(Ag0);
        float4 pa1 = *(const float4*)(Ag0 + 4);
        float4 pb0 = *(const float4*)(Ag1);
        float4 pb1 = *(const float4*)(Ag1 + 4);
        for (int k0 = 0; k0 < N_; k0 += 32) {
            f16x8 v0 = {(_Float16)pa0.x, (_Float16)pa0.y, (_Float16)pa0.z, (_Float16)pa0.w,
                        (_Float16)pa1.x, (_Float16)pa1.y, (_Float16)pa1.z, (_Float16)pa1.w};
            f16x8 v1 = {(_Float16)pb0.x, (_Float16)pb0.y, (_Float16)pb0.z, (_Float16)pb0.w,
                        (_Float16)pb1.x, (_Float16)pb1.y, (_Float16)pb1.z, (_Float16)pb1.w};
            *(f16x8*)la0 = v0;
            *(f16x8*)la1 = v1;
            gll16(gb0 + k0, lb0);
            gll16(gb1 + k0, lb1);
            if (k0 + 32 < N_) {   // prefetch next k-step; covered by MFMA phase
                pa0 = *(const float4*)(Ag0 + k0 + 32);
                pa1 = *(const float4*)(Ag0 + k0 + 36);
                pb0 = *(const float4*)(Ag1 + k0 + 32);
                pb1 = *(const float4*)(Ag1 + k0 + 36);
            }
            __syncthreads();
            f16x8 af[4], bf[4];
#pragma unroll
            for (int i = 0; i < 4; ++i) af[i] = *(const f16x8*)(As + (wr + i * 16 + lm) * 32 + q * 8);
#pragma unroll
            for (int j = 0; j < 4; ++j) bf[j] = *(const f16x8*)(Bs + (wc + j * 16 + lm) * 32 + q * 8);
#pragma unroll
            for (int i = 0; i < 4; ++i)
#pragma unroll
                for (int j = 0; j < 4; ++j)
                    acc[i][j] = __builtin_amdgcn_mfma_f32_16x16x32_f16(af[i], bf[j], acc[i][j], 0, 0, 0);
            __syncthreads();
        }
    } else {
        const _Float16* ga0 = Af + (size_t)(rr - 2) * (8 * 1048576) + (size_t)b * 1048576
                              + (size_t)(m0 + srow) * N_ + sk;
        const _Float16* ga1 = ga0 + (size_t)64 * N_;
        for (int k0 = 0; k0 < N_; k0 += 32) {
            gll16(ga0 + k0, la0);
            gll16(ga1 + k0, la1);
            gll16(gb0 + k0, lb0);
            gll16(gb1 + k0, lb1);
            __syncthreads();
            f16x8 af[4], bf[4];
#pragma unroll
            for (int i = 0; i < 4; ++i) af[i] = *(const f16x8*)(As + (wr + i * 16 + lm) * 32 + q * 8);
#pragma unroll
            for (int j = 0; j < 4; ++j) bf[j] = *(const f16x8*)(Bs + (wc + j * 16 + lm) * 32 + q * 8);
#pragma unroll
            for (int i = 0; i < 4; ++i)
#pragma unroll
                for (int j = 0; j < 4; ++j)
                    acc[i][j] = __builtin_amdgcn_mfma_f32_16x16x32_f16(af[i], bf[j], acc[i][j], 0, 0, 0);
            __syncthreads();
        }
    }
#pragma unroll
    for (int i = 0; i < 4; ++i)
#pragma unroll
        for (int j = 0; j < 4; ++j)
#pragma unroll
            for (int g = 0; g < 4; ++g) {
                int row = wr + i * 16 + q * 4 + g;
                int col = wc + j * 16 + lm;
                C[(size_t)(m0 + row) * 256 + (n0 + col)] = (_Float16)acc[i][j][g];
            }
}

// ======= final: out = max(AHW[0..3], HWN[0..2]) + bias =======
__global__ __launch_bounds__(256) void max_kernel(const _Float16* __restrict__ AHW,
                                                  const _Float16* __restrict__ HWN,
                                                  const float* __restrict__ bias,
                                                  float* __restrict__ out) {
    size_t i = ((size_t)blockIdx.x * 256 + threadIdx.x) * 8;
    const size_t slab = (size_t)B_ * N_ * OUT_;
    float m[8];
    f16x8 v = *(const f16x8*)(AHW + i);
#pragma unroll
    for (int e = 0; e < 8; ++e) m[e] = (float)v[e];
#pragma unroll
    for (int rr = 1; rr < 4; ++rr) {
        f16x8 w = *(const f16x8*)(AHW + rr * slab + i);
#pragma unroll
        for (int e = 0; e < 8; ++e) m[e] = fmaxf(m[e], (float)w[e]);
    }
#pragma unroll
    for (int j = 0; j < 3; ++j) {
        f16x8 w = *(const f16x8*)(HWN + j * slab + i);
#pragma unroll
        for (int e = 0; e < 8; ++e) m[e] = fmaxf(m[e], (float)w[e]);
    }
    size_t bidx = i & ((size_t)N_ * OUT_ - 1);
    float4 b0 = *(const float4*)(bias + bidx);
    float4 b1 = *(const float4*)(bias + bidx + 4);
    float4 o0 = {m[0] + b0.x, m[1] + b0.y, m[2] + b0.z, m[3] + b0.w};
    float4 o1 = {m[4] + b1.x, m[5] + b1.y, m[6] + b1.z, m[7] + b1.w};
    *(float4*)(out + i) = o0;
    *(float4*)(out + i + 4) = o1;
}

// ======================= round-1 fallback path (ws too small) ===========================
__global__ void cbias_kernel(const float* __restrict__ W, const float* __restrict__ We,
                             float* __restrict__ c) {
    int idx = blockIdx.x * 256 + threadIdx.x;
    if (idx >= NADJ_ * OUT_) return;
    int r = idx / OUT_, o = idx % OUT_;
    const float* Wr = W + (size_t)r * (F_ + REL_) * OUT_;
    float s = 0.f;
#pragma unroll
    for (int d = 0; d < REL_; ++d) s += We[r * REL_ + d] * Wr[(F_ + d) * OUT_ + o];
    c[idx] = s;
}

__global__ __launch_bounds__(256) void hw_kernel(const float* __restrict__ feat,
                                                 const float* __restrict__ W,
                                                 const float* __restrict__ cb,
                                                 _Float16* __restrict__ HWb) {
    __shared__ _Float16 As[64][32];
    __shared__ _Float16 Bs[64][32];
    const int mt = blockIdx.x, ct = blockIdx.y;
    const int tid = threadIdx.x, wave = tid >> 6, lane = tid & 63;
    const int r = (ct * 64) / OUT_;
    const int o0 = (ct * 64) % OUT_;
    const float* Bg = W + (size_t)r * (F_ + REL_) * OUT_ + o0;
    const int m0 = mt * 64;
    const int lm = lane & 15, q = lane >> 4;
    f32x4 acc[4] = {};
    for (int k0 = 0; k0 < F_; k0 += 32) {
        {
            int seg = (tid & 3) * 8, m = tid >> 2;
            const float* src = feat + (size_t)(m0 + m) * F_ + k0 + seg;
#pragma unroll
            for (int j = 0; j < 8; ++j) As[m][seg + j] = (_Float16)src[j];
        }
        {
            int kk = tid >> 3, ns = (tid & 7) * 8;
            const float* src = Bg + (size_t)(k0 + kk) * OUT_ + ns;
#pragma unroll
            for (int j = 0; j < 8; ++j) Bs[ns + j][kk] = (_Float16)src[j];
        }
        __syncthreads();
        f16x8 a = *(const f16x8*)&As[wave * 16 + lm][q * 8];
#pragma unroll
        for (int c4 = 0; c4 < 4; ++c4) {
            f16x8 b = *(const f16x8*)&Bs[c4 * 16 + lm][q * 8];
            acc[c4] = __builtin_amdgcn_mfma_f32_16x16x32_f16(a, b, acc[c4], 0, 0, 0);
        }
        __syncthreads();
    }
#pragma unroll
    for (int c4 = 0; c4 < 4; ++c4)
#pragma unroll
        for (int g = 0; g < 4; ++g) {
            int row = wave * 16 + (lane >> 4) * 4 + g;
            int col = c4 * 16 + lm;
            float v = acc[c4][g] + cb[r * OUT_ + o0 + col];
            HWb[((size_t)r * B_ * N_ + m0 + row) * OUT_ + o0 + col] = (_Float16)v;
        }
}

__global__ __launch_bounds__(256) void agg_kernel(const float* __restrict__ A1,
                                                  const float* __restrict__ A2,
                                                  const _Float16* __restrict__ HWb,
                                                  const float* __restrict__ bias,
                                                  float* __restrict__ out) {
    __shared__ _Float16 As[64][32];
    __shared__ _Float16 Bs[64][32];
    const int b = blockIdx.z, nt = blockIdx.y, ot = blockIdx.x;
    const int tid = threadIdx.x, wave = tid >> 6, lane = tid & 63;
    const int n0 = nt * 64, o0 = ot * 64;
    const int lm = lane & 15, q = lane >> 4;
    const size_t rstride = (size_t)B_ * N_ * OUT_;
    f32x4 mx[4];
#pragma unroll
    for (int i = 0; i < 4; ++i) mx[i] = f32x4{-1e30f, -1e30f, -1e30f, -1e30f};
#pragma unroll 1
    for (int rr = 0; rr < 4; ++rr) {
        const float* Ag = ((rr & 1) ? A2 : A1) + (size_t)b * N_ * N_;
        const bool tr = (rr >= 2);
        const int r = (rr < 2) ? rr : rr + 1;
        const _Float16* Bg = HWb + (size_t)r * rstride + (size_t)b * N_ * OUT_ + o0;
        f32x4 acc[4] = {};
        for (int k0 = 0; k0 < N_; k0 += 32) {
            if (!tr) {
                int seg = (tid & 3) * 8, m = tid >> 2;
                const float* src = Ag + (size_t)(n0 + m) * N_ + k0 + seg;
#pragma unroll
                for (int j = 0; j < 8; ++j) As[m][seg + j] = (_Float16)src[j];
            } else {
                int kk = tid >> 3, ms = (tid & 7) * 8;
                const float* src = Ag + (size_t)(k0 + kk) * N_ + n0 + ms;
#pragma unroll
                for (int j = 0; j < 8; ++j) As[ms + j][kk] = (_Float16)src[j];
            }
            {
                int kk = tid >> 3, ns = (tid & 7) * 8;
                const _Float16* src = Bg + (size_t)(k0 + kk) * OUT_ + ns;
#pragma unroll
                for (int j = 0; j < 8; ++j) Bs[ns + j][kk] = src[j];
            }
            __syncthreads();
            f16x8 a = *(const f16x8*)&As[wave * 16 + lm][q * 8];
#pragma unroll
            for (int c4 = 0; c4 < 4; ++c4) {
                f16x8 bb = *(const f16x8*)&Bs[c4 * 16 + lm][q * 8];
                acc[c4] = __builtin_amdgcn_mfma_f32_16x16x32_f16(a, bb, acc[c4], 0, 0, 0);
            }
            __syncthreads();
        }
#pragma unroll
        for (int c4 = 0; c4 < 4; ++c4)
#pragma unroll
            for (int g = 0; g < 4; ++g) mx[c4][g] = fmaxf(mx[c4][g], acc[c4][g]);
    }
#pragma unroll
    for (int c4 = 0; c4 < 4; ++c4)
#pragma unroll
        for (int g = 0; g < 4; ++g) {
            int row = wave * 16 + (lane >> 4) * 4 + g;
            int col = c4 * 16 + lm;
            size_t pos = ((size_t)b * N_ + n0 + row) * OUT_ + o0 + col;
            float v = mx[c4][g];
            v = fmaxf(v, (float)HWb[2 * rstride + pos]);
            v = fmaxf(v, (float)HWb[5 * rstride + pos]);
            v = fmaxf(v, (float)HWb[6 * rstride + pos]);
            out[pos] = v + bias[((size_t)(n0 + row)) * OUT_ + o0 + col];
        }
}

// ========================================================================================
extern "C" void kernel_launch(void* const* d_in, const int* in_sizes, int n_in,
                              void* d_out, int out_size, void* d_ws, size_t ws_size,
                              hipStream_t stream) {
    const float* feat = (const float*)d_in[0];
    const float* A1   = (const float*)d_in[1];
    const float* A2   = (const float*)d_in[2];
    const float* W    = (const float*)d_in[3];
    const float* We   = (const float*)d_in[4];
    const float* bias = (const float*)d_in[5];
    float* out = (float*)d_out;

    // fast-path ws layout (bytes)
    const size_t OFF_CB   = 0;          //   8 KB
    const size_t OFF_WT   = 8192;       // 896 KB
    const size_t OFF_FE   = 1048576;    //   4 MB
    const size_t OFF_AF   = 5242880;    //  32 MB used (2 transposed slabs)
    const size_t OFF_HWT  = 72351744;   //  16 MB
    const size_t OFF_HWN  = 89128960;   //  12 MB
    const size_t OFF_AHW  = 101711872;  //  16 MB
    const size_t WS_NEEDED = 118489088;

    if (ws_size >= WS_NEEDED) {
        float*    cbp = (float*)((char*)d_ws + OFF_CB);
        _Float16* WTp = (_Float16*)((char*)d_ws + OFF_WT);
        _Float16* Fe  = (_Float16*)((char*)d_ws + OFF_FE);
        _Float16* Af  = (_Float16*)((char*)d_ws + OFF_AF);
        _Float16* HWT = (_Float16*)((char*)d_ws + OFF_HWT);
        _Float16* HWN = (_Float16*)((char*)d_ws + OFF_HWN);
        _Float16* AHW = (_Float16*)((char*)d_ws + OFF_AHW);

        prep_kernel<<<2823, 256, 0, stream>>>(W, We, feat, cbp, WTp, Fe);
        convhw_kernel<<<4992, 256, 0, stream>>>(A1, A2, Fe, WTp, cbp, Af, HWT, HWN);
        p2_kernel<<<512, 256, 0, stream>>>(A1, A2, Af, HWT, AHW);
        max_kernel<<<1024, 256, 0, stream>>>(AHW, HWN, bias, out);
    } else {
        // round-1 fallback
        float* cb = (float*)d_ws;
        _Float16* HWb = (_Float16*)((char*)d_ws + 8192);
        cbias_kernel<<<7, 256, 0, stream>>>(W, We, cb);
        hw_kernel<<<dim3(128, 28), 256, 0, stream>>>(feat, W, cb, HWb);
        agg_kernel<<<dim3(4, 16, 8), 256, 0, stream>>>(A1, A2, HWb, bias, out);
    }
}